// Round 1
// baseline (202.417 us; speedup 1.0000x reference)
//
#include <hip/hip_runtime.h>
#include <hip/hip_bf16.h>

constexpr int CB = 4, CS = 1024, CH = 12, CDM = 768, CDH = 64;

typedef __attribute__((ext_vector_type(8))) short bf16x8;
typedef __attribute__((ext_vector_type(4))) float f32x4;

__device__ inline short f2bf(float f) {
    union { __hip_bfloat16 h; short s; } u;
    u.h = __float2bfloat16(f);
    return u.s;
}

// -------------------- Kernel 1: QKV projection --------------------
// grid: (B*S/64, H), block 256 (4 waves). Each wave: 16 rows x 192 cols.
// Outputs: q_ws [B,H,S,64] bf16 (pre-scaled by 1/8), k_ws [B,H,S,64] bf16,
//          vt_ws [B,H,64,S] bf16 (V transposed for the PV matmul).
__global__ __launch_bounds__(256) void qkv_kernel(
    const float* __restrict__ x,
    const float* __restrict__ wq, const float* __restrict__ bq,
    const float* __restrict__ wk, const float* __restrict__ bk,
    const float* __restrict__ wv, const float* __restrict__ bv,
    short* __restrict__ q_ws, short* __restrict__ k_ws, short* __restrict__ vt_ws)
{
    const int h = blockIdx.y;
    const int row0 = blockIdx.x * 64;          // over B*S
    const int tid = threadIdx.x;
    const int w = tid >> 6;
    const int l = tid & 63;
    const int l15 = l & 15, lg = l >> 4;

    __shared__ short wt[192 * 40];             // transposed weight chunk [col][k], pad 40
    __shared__ short vt[64 * 72];              // V transpose staging [d][s], pad 72

    const f32x4 zero4 = {0.f, 0.f, 0.f, 0.f};
    f32x4 acc[12];
    #pragma unroll
    for (int i = 0; i < 12; ++i) acc[i] = zero4;

    const float* xrow = x + (size_t)(row0 + w * 16 + l15) * (CH * CDM) + h * CDM;

    for (int kk = 0; kk < CDM; kk += 32) {
        __syncthreads();
        // stage W_Q|W_K|W_V chunk (32 k x 64 d each) transposed into wt
        for (int it = 0; it < 24; ++it) {
            int i = it * 256 + tid;
            int wsel = i >> 11;
            int rem = i & 2047;
            int mm = rem >> 6;
            int d = rem & 63;
            const float* wp = (wsel == 0) ? wq : (wsel == 1) ? wk : wv;
            float val = wp[((size_t)h * CDM + kk + mm) * CDH + d];
            wt[(wsel * 64 + d) * 40 + mm] = f2bf(val);
        }
        __syncthreads();

        // A fragment: lane reads 8 consecutive fp32 of its row
        float4 a0 = *(const float4*)(xrow + kk + lg * 8);
        float4 a1 = *(const float4*)(xrow + kk + lg * 8 + 4);
        bf16x8 a;
        a[0] = f2bf(a0.x); a[1] = f2bf(a0.y); a[2] = f2bf(a0.z); a[3] = f2bf(a0.w);
        a[4] = f2bf(a1.x); a[5] = f2bf(a1.y); a[6] = f2bf(a1.z); a[7] = f2bf(a1.w);

        #pragma unroll
        for (int ct = 0; ct < 12; ++ct) {
            bf16x8 bfr = *(const bf16x8*)(&wt[(ct * 16 + l15) * 40 + lg * 8]);
            acc[ct] = __builtin_amdgcn_mfma_f32_16x16x32_bf16(a, bfr, acc[ct], 0, 0, 0);
        }
    }

    const int b = row0 >> 10;
    const int sbase = row0 & (CS - 1);
    const size_t qkbase = (size_t)(b * CH + h) * CS;

    #pragma unroll
    for (int t = 0; t < 4; ++t) {
        int d = t * 16 + l15;
        float biasq = bq[h * CDH + d];
        float biask = bk[h * CDH + d];
        float biasv = bv[h * CDH + d];
        #pragma unroll
        for (int r = 0; r < 4; ++r) {
            int s = sbase + w * 16 + lg * 4 + r;
            q_ws[(qkbase + s) * CDH + d] = f2bf((acc[t][r] + biasq) * 0.125f);
            k_ws[(qkbase + s) * CDH + d] = f2bf(acc[4 + t][r] + biask);
            vt[d * 72 + (w * 16 + lg * 4 + r)] = f2bf(acc[8 + t][r] + biasv);
        }
    }
    __syncthreads();
    // write V^T coalesced: each thread one 32B chunk of a d-row
    {
        int dd = tid >> 2;
        int s0 = (tid & 3) * 16;
        size_t vdst = ((size_t)(b * CH + h) * CDH + dd) * CS + sbase + s0;
        *(bf16x8*)(vt_ws + vdst)     = *(const bf16x8*)(&vt[dd * 72 + s0]);
        *(bf16x8*)(vt_ws + vdst + 8) = *(const bf16x8*)(&vt[dd * 72 + s0 + 8]);
    }
}

// -------------------- Kernel 2: causal flash attention --------------------
// grid: (S/64, B*H), block 256. Wave w owns 16 q-rows; private trip count
// (no block barriers). K-blocks of 32 keys.
__global__ __launch_bounds__(256) void attn_kernel(
    const short* __restrict__ q_ws, const short* __restrict__ k_ws,
    const short* __restrict__ vt_ws, short* __restrict__ z_ws)
{
    const int bh = blockIdx.y;
    const int tid = threadIdx.x;
    const int w = tid >> 6, l = tid & 63;
    const int l15 = l & 15, lg = l >> 4;
    const int q0 = blockIdx.x * 64 + w * 16;

    __shared__ short pls_all[4][16 * 40];      // per-wave P tile, pad 40
    short* pls = &pls_all[w][0];

    const short* qbase = q_ws + ((size_t)bh * CS + q0 + l15) * CDH + lg * 8;
    bf16x8 aq0 = *(const bf16x8*)(qbase);
    bf16x8 aq1 = *(const bf16x8*)(qbase + 32);

    const f32x4 zero4 = {0.f, 0.f, 0.f, 0.f};
    f32x4 acc_o[4];
    #pragma unroll
    for (int i = 0; i < 4; ++i) acc_o[i] = zero4;
    float m_r[4] = {-1e30f, -1e30f, -1e30f, -1e30f};
    float l_r[4] = {0.f, 0.f, 0.f, 0.f};

    const int nkb = (q0 + 15) / 32 + 1;
    for (int kb = 0; kb < nkb; ++kb) {
        const int k0 = kb * 32;
        f32x4 s0 = zero4, s1 = zero4;
        {
            const short* kp0 = k_ws + ((size_t)bh * CS + k0 + l15) * CDH + lg * 8;
            const short* kp1 = kp0 + 16 * CDH;
            bf16x8 b00 = *(const bf16x8*)(kp0);
            bf16x8 b01 = *(const bf16x8*)(kp0 + 32);
            bf16x8 b10 = *(const bf16x8*)(kp1);
            bf16x8 b11 = *(const bf16x8*)(kp1 + 32);
            s0 = __builtin_amdgcn_mfma_f32_16x16x32_bf16(aq0, b00, s0, 0, 0, 0);
            s0 = __builtin_amdgcn_mfma_f32_16x16x32_bf16(aq1, b01, s0, 0, 0, 0);
            s1 = __builtin_amdgcn_mfma_f32_16x16x32_bf16(aq0, b10, s1, 0, 0, 0);
            s1 = __builtin_amdgcn_mfma_f32_16x16x32_bf16(aq1, b11, s1, 0, 0, 0);
        }
        if (k0 + 31 > q0) {   // diagonal block: causal mask
            #pragma unroll
            for (int r = 0; r < 4; ++r) {
                int row = q0 + lg * 4 + r;
                if (k0 + l15 > row)      s0[r] = -1e30f;
                if (k0 + 16 + l15 > row) s1[r] = -1e30f;
            }
        }
        // online softmax (wave-parallel row reduce over 16-lane groups)
        #pragma unroll
        for (int r = 0; r < 4; ++r) {
            float v = fmaxf(s0[r], s1[r]);
            v = fmaxf(v, __shfl_xor(v, 1));
            v = fmaxf(v, __shfl_xor(v, 2));
            v = fmaxf(v, __shfl_xor(v, 4));
            v = fmaxf(v, __shfl_xor(v, 8));
            float mnew = fmaxf(m_r[r], v);
            float scale = __expf(m_r[r] - mnew);
            m_r[r] = mnew;
            float p0 = __expf(s0[r] - mnew);
            float p1 = __expf(s1[r] - mnew);
            s0[r] = p0; s1[r] = p1;
            float rs = p0 + p1;
            rs += __shfl_xor(rs, 1);
            rs += __shfl_xor(rs, 2);
            rs += __shfl_xor(rs, 4);
            rs += __shfl_xor(rs, 8);
            l_r[r] = l_r[r] * scale + rs;
            acc_o[0][r] *= scale; acc_o[1][r] *= scale;
            acc_o[2][r] *= scale; acc_o[3][r] *= scale;
        }
        // P -> LDS (C layout) then re-read as A fragment
        #pragma unroll
        for (int r = 0; r < 4; ++r) {
            pls[(lg * 4 + r) * 40 + l15]      = f2bf(s0[r]);
            pls[(lg * 4 + r) * 40 + 16 + l15] = f2bf(s1[r]);
        }
        asm volatile("s_waitcnt lgkmcnt(0)" ::: "memory");
        bf16x8 pa = *(const bf16x8*)(&pls[l15 * 40 + lg * 8]);
        #pragma unroll
        for (int ct = 0; ct < 4; ++ct) {
            const short* vb = vt_ws + ((size_t)bh * CDH + ct * 16 + l15) * CS + k0 + lg * 8;
            bf16x8 bv = *(const bf16x8*)(vb);
            acc_o[ct] = __builtin_amdgcn_mfma_f32_16x16x32_bf16(pa, bv, acc_o[ct], 0, 0, 0);
        }
    }
    #pragma unroll
    for (int ct = 0; ct < 4; ++ct) {
        #pragma unroll
        for (int r = 0; r < 4; ++r) {
            float z = acc_o[ct][r] / l_r[r];
            z_ws[((size_t)bh * CS + q0 + lg * 4 + r) * CDH + ct * 16 + l15] = f2bf(z);
        }
    }
}

// -------------------- Kernel 3: output projection --------------------
// grid: ((S/64)*4, B*H), block 256. 64 q-rows x 192 out-cols per workgroup.
__global__ __launch_bounds__(256) void out_kernel(
    const short* __restrict__ z_ws, const float* __restrict__ wo,
    const float* __restrict__ bo, float* __restrict__ out)
{
    const int bh = blockIdx.y;
    const int b = bh / CH, h = bh % CH;
    const int qblk = blockIdx.x >> 2;
    const int n0 = (blockIdx.x & 3) * 192;
    const int tid = threadIdx.x;
    const int w = tid >> 6, l = tid & 63;
    const int l15 = l & 15, lg = l >> 4;

    __shared__ short wbT[192 * 72];            // W_O slice transposed [m][d], pad 72
    for (int it = 0; it < 48; ++it) {
        int i = it * 256 + tid;
        int d = i / 192, mm = i % 192;
        wbT[mm * 72 + d] = f2bf(wo[((size_t)h * CDH + d) * CDM + n0 + mm]);
    }
    __syncthreads();

    const int q0 = qblk * 64 + w * 16;
    const short* zbase = z_ws + ((size_t)bh * CS + q0 + l15) * CDH + lg * 8;
    bf16x8 a0 = *(const bf16x8*)(zbase);
    bf16x8 a1 = *(const bf16x8*)(zbase + 32);

    const f32x4 zero4 = {0.f, 0.f, 0.f, 0.f};
    f32x4 acc[12];
    #pragma unroll
    for (int i = 0; i < 12; ++i) acc[i] = zero4;
    #pragma unroll
    for (int ct = 0; ct < 12; ++ct) {
        bf16x8 b0 = *(const bf16x8*)(&wbT[(ct * 16 + l15) * 72 + lg * 8]);
        bf16x8 b1 = *(const bf16x8*)(&wbT[(ct * 16 + l15) * 72 + 32 + lg * 8]);
        acc[ct] = __builtin_amdgcn_mfma_f32_16x16x32_bf16(a0, b0, acc[ct], 0, 0, 0);
        acc[ct] = __builtin_amdgcn_mfma_f32_16x16x32_bf16(a1, b1, acc[ct], 0, 0, 0);
    }
    #pragma unroll
    for (int ct = 0; ct < 12; ++ct) {
        int mcol = n0 + ct * 16 + l15;
        float bias = bo[mcol] * (1.0f / CH);
        #pragma unroll
        for (int r = 0; r < 4; ++r) {
            int q = q0 + lg * 4 + r;
            out[(((size_t)b * CS + q) * CH + h) * CDM + mcol] = acc[ct][r] + bias;
        }
    }
}

extern "C" void kernel_launch(void* const* d_in, const int* in_sizes, int n_in,
                              void* d_out, int out_size, void* d_ws, size_t ws_size,
                              hipStream_t stream) {
    const float* x  = (const float*)d_in[0];
    const float* wq = (const float*)d_in[1];
    const float* bq = (const float*)d_in[2];
    const float* wk = (const float*)d_in[3];
    const float* bk = (const float*)d_in[4];
    const float* wv = (const float*)d_in[5];
    const float* bv = (const float*)d_in[6];
    const float* wo = (const float*)d_in[7];
    const float* bo = (const float*)d_in[8];
    float* out = (float*)d_out;

    const size_t tsz = (size_t)CB * CH * CS * CDH;   // 3,145,728 elems
    short* q_ws  = (short*)d_ws;
    short* k_ws  = q_ws + tsz;
    short* vt_ws = k_ws + tsz;
    short* z_ws  = vt_ws + tsz;

    qkv_kernel<<<dim3(CB * CS / 64, CH), 256, 0, stream>>>(
        x, wq, bq, wk, bk, wv, bv, q_ws, k_ws, vt_ws);
    attn_kernel<<<dim3(CS / 64, CB * CH), 256, 0, stream>>>(
        q_ws, k_ws, vt_ws, z_ws);
    out_kernel<<<dim3((CS / 64) * 4, CB * CH), 256, 0, stream>>>(
        z_ws, wo, bo, out);
}